// Round 7
// baseline (403.464 us; speedup 1.0000x reference)
//
#include <hip/hip_runtime.h>

#define P 7
#define PP 49            // 7*7 pixels per ROI
#define CMAX 256         // channels
#define G 8              // ROIs per cluster (per block)
#define CSPLIT 8         // channel slices -> CMAX/CSPLIT channels per block
#define CSLICE 32        // channels per block
#define NBINS 256        // 4 levels x 8x8 spatial cells
#define CHUNK 8          // clusters per XCD-chunk (balance grain)
#define BUFCH 320        // 16B chunks per wave staging buffer (>= max region, proven)

// d_ws layout in u32 words:
//   [2560,4608)  perm (sorted roi indices, capacity 2048)
#define WS_PERM   2560

typedef float f4a4  __attribute__((ext_vector_type(4), aligned(4)));   // global 16B load (4B aligned)
typedef float f4a16 __attribute__((ext_vector_type(4), aligned(16)));  // LDS 16B store

struct PixParam { int x0, y0; float w00, w01, w10, w11; };

__device__ __forceinline__ int roi_level(float x1, float y1, float x2, float y2) {
    const float area = __fmul_rn(__fsub_rn(y2, y1), __fsub_rn(x2, x1));
    int lvl = (int)rintf(log2f(sqrtf(fmaxf(area, 0.0f)) / 224.0f)) + 4;
    return lvl < 2 ? 2 : (lvl > 5 ? 5 : lvl);
}

// ---- fused prep: hist + scan + scatter, one block, everything in LDS ----
__global__ __launch_bounds__(256) void prep_kernel(
    const float* __restrict__ rois, int n, unsigned* __restrict__ ws)
{
    __shared__ unsigned s_hist[NBINS];
    __shared__ unsigned s_cur[NBINS];
    const int t = threadIdx.x;
    s_hist[t] = 0u;
    __syncthreads();

    unsigned bloc[8];
    #pragma unroll
    for (int i = 0; i < 8; ++i) {
        const int r = t + i * 256;
        bloc[i] = 0u;
        if (r < n) {
            const float x1 = rois[r*4+0], y1 = rois[r*4+1];
            const float x2 = rois[r*4+2], y2 = rois[r*4+3];
            const int lvl = roi_level(x1, y1, x2, y2);
            int cx = ((int)(__fmul_rn(__fadd_rn(x1, x2), 0.5f))) >> 7; cx = min(cx, 7);
            int cy = ((int)(__fmul_rn(__fadd_rn(y1, y2), 0.5f))) >> 7; cy = min(cy, 7);
            const unsigned b = (unsigned)(((lvl - 2) << 6) | (cy << 3) | cx);
            bloc[i] = b;
            atomicAdd(&s_hist[b], 1u);
        }
    }
    __syncthreads();

    const unsigned h = s_hist[t];
    s_cur[t] = h;
    __syncthreads();
    for (int off = 1; off < NBINS; off <<= 1) {
        const unsigned v = (t >= off) ? s_cur[t - off] : 0u;
        __syncthreads();
        s_cur[t] += v;
        __syncthreads();
    }
    s_cur[t] -= h;
    __syncthreads();

    #pragma unroll
    for (int i = 0; i < 8; ++i) {
        const int r = t + i * 256;
        if (r < n) {
            const unsigned pos = atomicAdd(&s_cur[bloc[i]], 1u);
            ws[WS_PERM + pos] = (unsigned)r;
        }
    }
}

// Per-g state for the staged-gather loop (all fields statically accessed).
struct GState {
    const float* fm;
    int hw, H, tot, NC, W4x4, offmax, chbase;
    long long ob;
    int o0, o1, o2, o3, o4;   // per-lane chunk global word-offsets (incl. region base)
    int tA, tB;               // per-lane tap word offsets within the LDS region
    float w00, w01, w10, w11;
    int outb;                 // per-lane store base (valid iff ob >= 0)
};

struct C5 { f4a4 c0, c1, c2, c3, c4; };

__global__ __launch_bounds__(256) void roialign_main(
    const float* __restrict__ p2, const float* __restrict__ p3,
    const float* __restrict__ p4, const float* __restrict__ p5,
    const float* __restrict__ rois, const unsigned* __restrict__ ws,
    float* __restrict__ out, int n)
{
    __shared__ PixParam sp[G * PP];
    __shared__ const float* fm_s[G];
    __shared__ int hw_s[G];
    __shared__ int H_s[G];
    __shared__ long long obase_s[G];
    __shared__ float box_s[G][4];
    __shared__ float lbuf[4][BUFCH * 4];       // per-wave region buffer (5120B each)

    const int nclust = (n + G - 1) / G;

    // Balanced XCD chunking (round-3, kept): CHUNK consecutive sorted clusters
    // per XCD-chunk, chunks dealt round-robin across XCDs.
    const int pb  = blockIdx.x;
    const int xcd = pb & 7, jb = pb >> 3;
    const int chunk = (jb >> 6) * 8 + xcd;
    const int within = jb & 63;
    const int cl = chunk * CHUNK + (within & 7);
    const int cb = within >> 3;
    if (cl >= nclust) return;
    const int t = threadIdx.x;

    // ---- per-ROI setup ----
    if (t < G) {
        const int gi = cl * G + t;
        long long ob = -1; const float* fm = p2; int H = 4; int hw = 0;
        float bx1 = 0.f, by1 = 0.f, bx2 = 0.f, by2 = 0.f;
        if (gi < n) {
            const int rr = (int)ws[WS_PERM + gi];
            bx1 = rois[rr*4+0]; by1 = rois[rr*4+1];
            bx2 = rois[rr*4+2]; by2 = rois[rr*4+3];
            const int lvl = roi_level(bx1, by1, bx2, by2);
            H = 1024 >> lvl;
            hw = H * H;
            fm = (lvl == 2) ? p2 : (lvl == 3) ? p3 : (lvl == 4) ? p4 : p5;
            ob = (long long)rr * (CMAX * PP);
        }
        fm_s[t] = fm; hw_s[t] = hw; H_s[t] = H; obase_s[t] = ob;
        box_s[t][0] = bx1; box_s[t][1] = by1; box_s[t][2] = bx2; box_s[t][3] = by2;
    }
    __syncthreads();

    // ---- per-(roi,pixel) params into LDS (identical arithmetic to verified R3) ----
    for (int idx = t; idx < G * PP; idx += 256) {
        const int g = idx / PP, pix = idx % PP;
        PixParam pp; pp.x0 = 0; pp.y0 = 0;
        pp.w00 = 0.f; pp.w01 = 0.f; pp.w10 = 0.f; pp.w11 = 0.f;
        if (obase_s[g] >= 0) {
            const float x1 = box_s[g][0], y1 = box_s[g][1];
            const float x2 = box_s[g][2], y2 = box_s[g][3];
            const int H = H_s[g];
            const int py = pix / P, px = pix % P;
            const float inv = 1.0f / 1024.0f;
            const float by1 = __fmul_rn(y1, inv), bx1 = __fmul_rn(x1, inv);
            const float by2 = __fmul_rn(y2, inv), bx2 = __fmul_rn(x2, inv);
            const float Hm1 = (float)(H - 1);
            const float ty = (float)py / 6.0f;
            const float tx = (float)px / 6.0f;
            const float vy = __fmul_rn(__fadd_rn(by1, __fmul_rn(ty, __fsub_rn(by2, by1))), Hm1);
            const float vx = __fmul_rn(__fadd_rn(bx1, __fmul_rn(tx, __fsub_rn(bx2, bx1))), Hm1);
            const bool vldy = (vy >= 0.0f) && (vy <= Hm1);
            const bool vldx = (vx >= 0.0f) && (vx <= Hm1);
            const float yc = fminf(fmaxf(vy, 0.0f), Hm1);
            const float xc = fminf(fmaxf(vx, 0.0f), Hm1);
            const int y0 = (int)floorf(yc);
            const int x0 = (int)floorf(xc);
            const float ly = __fsub_rn(yc, (float)y0);
            const float lx = __fsub_rn(xc, (float)x0);
            const float m = (vldy && vldx) ? 1.0f : 0.0f;
            const float wy0 = m * (1.0f - ly), wy1 = m * ly;
            const float wx0 = 1.0f - lx,      wx1 = lx;
            pp.x0 = x0;  pp.y0 = y0;
            pp.w00 = wy0 * wx0;  pp.w01 = wy0 * wx1;
            pp.w10 = wy1 * wx0;  pp.w11 = wy1 * wx1;
        }
        sp[idx] = pp;
    }

    const int w    = t >> 6;
    const int lane = t & 63;
    const int pix  = lane < PP ? lane : PP - 1;
    const bool act = (lane < PP);
    float* lb = &lbuf[w][0];
    const int chb0 = cb * CSLICE + w * 8;     // this wave's first channel

    // zero own buffer (stale-LDS NaN guard for weight-0 padding taps)
    {
        f4a16 z = {0.f, 0.f, 0.f, 0.f};
        #pragma unroll
        for (int ic = 0; ic < 5; ++ic)
            *(f4a16*)(lb + (lane + ic * 64) * 4) = z;
    }
    __syncthreads();

    // per-g state loader (wave-uniform rect from monotonic corner pixels 0/6/42)
    auto load_g = [&](int g) {
        GState s;
        s.fm = fm_s[g]; s.hw = hw_s[g]; s.H = H_s[g]; s.ob = obase_s[g];
        const int xlo = sp[g*PP + 0].x0, ylo = sp[g*PP + 0].y0;
        const int x6  = sp[g*PP + 6].x0, y42 = sp[g*PP + 42].y0;
        const int H = s.H;
        const int xhi = min(x6 + 1, H - 1), yhi = min(y42 + 1, H - 1);
        const int Wr = xhi - xlo + 1, Hr = yhi - ylo + 1;
        const int W4 = (Wr + 3) >> 2;
        s.W4x4 = W4 << 2;
        s.tot = Hr * W4;                       // 16B chunks in region (<= BUFCH)
        s.NC = (s.tot + 63) >> 6;              // staging instrs (1..5)
        s.offmax = max(512 * s.hw - 4, 0);     // allocation guard (words)
        s.chbase = chb0 * s.hw;
        const int gbase = ylo * H + xlo;
        const float fr = 1.0f / (float)W4;
        #define CHUNK_OFF(IC, DST) { \
            int ci = min(lane + IC * 64, s.tot - 1); \
            int rr = (int)((float)ci * fr); \
            int rm = ci - rr * W4; \
            if (rm >= W4) { rm -= W4; ++rr; } else if (rm < 0) { rm += W4; --rr; } \
            DST = gbase + rr * H + (rm << 2); }
        CHUNK_OFF(0, s.o0) CHUNK_OFF(1, s.o1) CHUNK_OFF(2, s.o2)
        CHUNK_OFF(3, s.o3) CHUNK_OFF(4, s.o4)
        #undef CHUNK_OFF
        const PixParam pp = sp[g*PP + pix];
        const int xl = pp.x0 - xlo, yl = pp.y0 - ylo;
        const int yb = min(pp.y0 + 1, H - 1) - ylo;
        s.tA = yl * s.W4x4 + xl;
        s.tB = yb * s.W4x4 + xl;
        s.w00 = pp.w00; s.w01 = pp.w01; s.w10 = pp.w10; s.w11 = pp.w11;
        s.outb = (int)s.ob + chb0 * PP + pix;
        return s;
    };

    auto issue = [&](const GState& s, int j, C5& c) {
        const int choff = s.chbase + j * s.hw;
        if (0 < s.NC) c.c0 = *(const f4a4*)(s.fm + min(choff + s.o0, s.offmax));
        if (1 < s.NC) c.c1 = *(const f4a4*)(s.fm + min(choff + s.o1, s.offmax));
        if (2 < s.NC) c.c2 = *(const f4a4*)(s.fm + min(choff + s.o2, s.offmax));
        if (3 < s.NC) c.c3 = *(const f4a4*)(s.fm + min(choff + s.o3, s.offmax));
        if (4 < s.NC) c.c4 = *(const f4a4*)(s.fm + min(choff + s.o4, s.offmax));
    };

    auto write_lds = [&](const GState& s, const C5& c) {
        if (0 < s.NC) *(f4a16*)(lb + min(lane,           s.tot - 1) * 4) = c.c0;
        if (1 < s.NC) *(f4a16*)(lb + min(lane + 64,      s.tot - 1) * 4) = c.c1;
        if (2 < s.NC) *(f4a16*)(lb + min(lane + 128,     s.tot - 1) * 4) = c.c2;
        if (3 < s.NC) *(f4a16*)(lb + min(lane + 192,     s.tot - 1) * 4) = c.c3;
        if (4 < s.NC) *(f4a16*)(lb + min(lane + 256,     s.tot - 1) * 4) = c.c4;
    };

    auto taps_store = [&](const GState& s, int j) {
        const float t0 = lb[s.tA], t1 = lb[s.tA + 1];
        const float b0 = lb[s.tB], b1 = lb[s.tB + 1];
        const float v = t0 * s.w00 + t1 * s.w01 + b0 * s.w10 + b1 * s.w11;
        if (act && s.ob >= 0) out[s.outb + j * PP] = v;
    };

    // ---- main loop: 64 items (8 roi x 8 ch per wave), reg-double-buffered
    // staging (T14: issue next -> write current -> tap current), no barriers ----
    GState A = load_g(0), B;
    C5 cA, cB;
    issue(A, 0, cA);
    for (int g = 0; g < G; ++g) {
        #pragma unroll
        for (int jj = 0; jj < 4; ++jj) {
            const int je = jj * 2, jo = je + 1;
            issue(A, jo, cB);              // next item's loads in flight
            write_lds(A, cA);              // waits only cA's vmcnt
            taps_store(A, je);
            if (jo < 7) {
                issue(A, jo + 1, cA);
            } else if (g + 1 < G) {
                B = load_g(g + 1);
                issue(B, 0, cA);
            }
            write_lds(A, cB);
            taps_store(A, jo);
        }
        if (g + 1 < G) A = B;
    }
}

extern "C" void kernel_launch(void* const* d_in, const int* in_sizes, int n_in,
                              void* d_out, int out_size, void* d_ws, size_t ws_size,
                              hipStream_t stream) {
    const float* p2   = (const float*)d_in[0];
    const float* p3   = (const float*)d_in[1];
    const float* p4   = (const float*)d_in[2];
    const float* p5   = (const float*)d_in[3];
    const float* rois = (const float*)d_in[4];
    float* out = (float*)d_out;
    unsigned* ws = (unsigned*)d_ws;
    const int n = in_sizes[4] / 4;            // B*R = 2000

    prep_kernel<<<1, 256, 0, stream>>>(rois, n, ws);

    const int nclust  = (n + G - 1) / G;              // 250
    const int nchunk  = (nclust + CHUNK - 1) / CHUNK; // 32
    const int nchunk8 = (nchunk + 7) & ~7;            // 32
    const int nblocks = nchunk8 * CHUNK * CSPLIT;     // 2048
    roialign_main<<<nblocks, 256, 0, stream>>>(p2, p3, p4, p5, rois, ws, out, n);
}